// Round 1
// baseline (194.652 us; speedup 1.0000x reference)
//
#include <hip/hip_runtime.h>

// Volume rendering marcher: one wave (64 lanes) per ray, 4 samples per lane.
// S = 256, N = 32768.
//
// per-element: x = density + shift
//              sp = softplus(x); m = exp(-sp * t)   (one_minus_alpha)
//              alpha = 1 - m
// cumprod(m) over s via: local 4-elem prefix product + wave shfl_up scan.
// weights = T_excl * alpha;  T_last = total product.
// rgb_marched = sum_s w_s * rgb_s + T_last * bg.

__global__ __launch_bounds__(256) void march_kernel(
    const float* __restrict__ density,   // [N,256]
    const float* __restrict__ shift,     // [256]
    const float* __restrict__ rgb,       // [N,256,3]
    const float* __restrict__ bg,        // [3]
    const int*   __restrict__ interval_p,
    float* __restrict__ out_rgb,         // [N,3]
    float* __restrict__ out_weights,     // [N,256]
    float* __restrict__ out_alast,       // [N]
    int n_rays)
{
    const int wave = threadIdx.x >> 6;
    const int lane = threadIdx.x & 63;
    const int ray  = blockIdx.x * 4 + wave;
    if (ray >= n_rays) return;

    const float t = (float)(*interval_p);

    // ---- load 4 density samples + shift (coalesced float4) ----
    const float4 d4 = *reinterpret_cast<const float4*>(density + (size_t)ray * 256 + lane * 4);
    const float4 s4 = *reinterpret_cast<const float4*>(shift + lane * 4);

    float x0 = d4.x + s4.x;
    float x1 = d4.y + s4.y;
    float x2 = d4.z + s4.z;
    float x3 = d4.w + s4.w;

    // stable softplus
    auto softplus = [](float x) {
        return (x > 0.0f) ? x + log1pf(expf(-x)) : log1pf(expf(x));
    };

    // one_minus_alpha m = exp(-softplus(x) * t)
    float m0 = expf(-softplus(x0) * t);
    float m1 = expf(-softplus(x1) * t);
    float m2 = expf(-softplus(x2) * t);
    float m3 = expf(-softplus(x3) * t);

    float a0 = 1.0f - m0;
    float a1 = 1.0f - m1;
    float a2 = 1.0f - m2;
    float a3 = 1.0f - m3;

    // ---- local prefix products over the lane's 4 samples ----
    float p1 = m0;
    float p2 = p1 * m1;
    float p3 = p2 * m2;
    float p4 = p3 * m3;   // product of all 4

    // ---- wave-wide inclusive scan (product) of p4 across 64 lanes ----
    float incl = p4;
    #pragma unroll
    for (int off = 1; off < 64; off <<= 1) {
        float v = __shfl_up(incl, off, 64);
        if (lane >= off) incl *= v;
    }
    float excl = __shfl_up(incl, 1, 64);   // product of all samples before this lane
    if (lane == 0) excl = 1.0f;

    // T_excl per sample, weights
    float w0 = excl * a0;
    float w1 = excl * p1 * a1;
    float w2 = excl * p2 * a2;
    float w3 = excl * p3 * a3;

    *reinterpret_cast<float4*>(out_weights + (size_t)ray * 256 + lane * 4) =
        make_float4(w0, w1, w2, w3);

    const float T_last = __shfl(incl, 63, 64);  // total product = alphainv_last

    // ---- rgb weighted sum: 12 contiguous floats per lane (3x float4) ----
    const float* rp = rgb + (size_t)ray * 768 + lane * 12;
    const float4 r0 = *reinterpret_cast<const float4*>(rp);
    const float4 r1 = *reinterpret_cast<const float4*>(rp + 4);
    const float4 r2 = *reinterpret_cast<const float4*>(rp + 8);

    // sample j channel layout:
    //  s0: r0.x r0.y r0.z | s1: r0.w r1.x r1.y | s2: r1.z r1.w r2.x | s3: r2.y r2.z r2.w
    float cr = w0 * r0.x + w1 * r0.w + w2 * r1.z + w3 * r2.y;
    float cg = w0 * r0.y + w1 * r1.x + w2 * r1.w + w3 * r2.z;
    float cb = w0 * r0.z + w1 * r1.y + w2 * r2.x + w3 * r2.w;

    // ---- wave reduction ----
    #pragma unroll
    for (int off = 32; off >= 1; off >>= 1) {
        cr += __shfl_xor(cr, off, 64);
        cg += __shfl_xor(cg, off, 64);
        cb += __shfl_xor(cb, off, 64);
    }

    if (lane == 0) {
        out_rgb[(size_t)ray * 3 + 0] = cr + T_last * bg[0];
        out_rgb[(size_t)ray * 3 + 1] = cg + T_last * bg[1];
        out_rgb[(size_t)ray * 3 + 2] = cb + T_last * bg[2];
        out_alast[ray] = T_last;
    }
}

extern "C" void kernel_launch(void* const* d_in, const int* in_sizes, int n_in,
                              void* d_out, int out_size, void* d_ws, size_t ws_size,
                              hipStream_t stream) {
    const float* density  = (const float*)d_in[0];
    const float* shift    = (const float*)d_in[1];
    const float* rgb      = (const float*)d_in[2];
    const float* bg       = (const float*)d_in[3];
    const int*   interval = (const int*)d_in[4];

    const int n_rays = in_sizes[0] / 256;   // 32768

    float* out = (float*)d_out;
    float* out_rgb     = out;                           // N*3
    float* out_weights = out + (size_t)n_rays * 3;      // N*256
    float* out_alast   = out + (size_t)n_rays * 3 + (size_t)n_rays * 256;  // N

    const int waves_per_block = 4;  // 256 threads
    const int grid = (n_rays + waves_per_block - 1) / waves_per_block;

    march_kernel<<<grid, 256, 0, stream>>>(
        density, shift, rgb, bg, interval,
        out_rgb, out_weights, out_alast, n_rays);
}

// Round 2
// 185.557 us; speedup vs baseline: 1.0490x; 1.0490x over previous
//
#include <hip/hip_runtime.h>

// Volume rendering marcher: one wave (64 lanes) per ray, 4 samples per lane.
// S = 256, N = 32768.
//
// VALU-bound fix (R1): libm expf/log1pf -> native v_exp/v_log/v_rcp.
// t==1 fast path (wave-uniform branch): m = exp(-softplus(x)) = 1/(1+e^x).

__device__ __forceinline__ float one_minus_alpha_t1(float x) {
    // m = 1/(1 + e^x), native exp + native rcp.
    // x >= ~88 -> __expf = inf -> rcp = 0 (correct limit).
    return __builtin_amdgcn_rcpf(1.0f + __expf(x));
}

__device__ __forceinline__ float one_minus_alpha_gen(float x, float t) {
    // m = exp(-t * softplus(x)), stable softplus with native exp/log.
    float sp = fmaxf(x, 0.0f) + __logf(1.0f + __expf(-fabsf(x)));
    return __expf(-sp * t);
}

__global__ __launch_bounds__(256) void march_kernel(
    const float* __restrict__ density,   // [N,256]
    const float* __restrict__ shift,     // [256]
    const float* __restrict__ rgb,       // [N,256,3]
    const float* __restrict__ bg,        // [3]
    const int*   __restrict__ interval_p,
    float* __restrict__ out_rgb,         // [N,3]
    float* __restrict__ out_weights,     // [N,256]
    float* __restrict__ out_alast,       // [N]
    int n_rays)
{
    const int wave = threadIdx.x >> 6;
    const int lane = threadIdx.x & 63;
    const int ray  = blockIdx.x * 4 + wave;
    if (ray >= n_rays) return;

    const float t = (float)(*interval_p);
    const bool t_is_one = (t == 1.0f);   // wave-uniform

    // ---- load 4 density samples + shift (coalesced float4) ----
    const float4 d4 = *reinterpret_cast<const float4*>(density + (size_t)ray * 256 + lane * 4);
    const float4 s4 = *reinterpret_cast<const float4*>(shift + lane * 4);

    const float x0 = d4.x + s4.x;
    const float x1 = d4.y + s4.y;
    const float x2 = d4.z + s4.z;
    const float x3 = d4.w + s4.w;

    float m0, m1, m2, m3;
    if (t_is_one) {
        m0 = one_minus_alpha_t1(x0);
        m1 = one_minus_alpha_t1(x1);
        m2 = one_minus_alpha_t1(x2);
        m3 = one_minus_alpha_t1(x3);
    } else {
        m0 = one_minus_alpha_gen(x0, t);
        m1 = one_minus_alpha_gen(x1, t);
        m2 = one_minus_alpha_gen(x2, t);
        m3 = one_minus_alpha_gen(x3, t);
    }

    const float a0 = 1.0f - m0;
    const float a1 = 1.0f - m1;
    const float a2 = 1.0f - m2;
    const float a3 = 1.0f - m3;

    // ---- local prefix products over the lane's 4 samples ----
    const float p1 = m0;
    const float p2 = p1 * m1;
    const float p3 = p2 * m2;
    const float p4 = p3 * m3;   // product of all 4

    // ---- wave-wide inclusive scan (product) of p4 across 64 lanes ----
    float incl = p4;
    #pragma unroll
    for (int off = 1; off < 64; off <<= 1) {
        float v = __shfl_up(incl, off, 64);
        if (lane >= off) incl *= v;
    }
    float excl = __shfl_up(incl, 1, 64);   // product of all samples before this lane
    if (lane == 0) excl = 1.0f;

    // T_excl per sample, weights
    const float w0 = excl * a0;
    const float w1 = excl * p1 * a1;
    const float w2 = excl * p2 * a2;
    const float w3 = excl * p3 * a3;

    *reinterpret_cast<float4*>(out_weights + (size_t)ray * 256 + lane * 4) =
        make_float4(w0, w1, w2, w3);

    const float T_last = __shfl(incl, 63, 64);  // total product = alphainv_last

    // ---- rgb weighted sum: 12 contiguous floats per lane (3x float4) ----
    const float* rp = rgb + (size_t)ray * 768 + lane * 12;
    const float4 r0 = *reinterpret_cast<const float4*>(rp);
    const float4 r1 = *reinterpret_cast<const float4*>(rp + 4);
    const float4 r2 = *reinterpret_cast<const float4*>(rp + 8);

    // sample j channel layout:
    //  s0: r0.x r0.y r0.z | s1: r0.w r1.x r1.y | s2: r1.z r1.w r2.x | s3: r2.y r2.z r2.w
    float cr = w0 * r0.x + w1 * r0.w + w2 * r1.z + w3 * r2.y;
    float cg = w0 * r0.y + w1 * r1.x + w2 * r1.w + w3 * r2.z;
    float cb = w0 * r0.z + w1 * r1.y + w2 * r2.x + w3 * r2.w;

    // ---- wave reduction ----
    #pragma unroll
    for (int off = 32; off >= 1; off >>= 1) {
        cr += __shfl_xor(cr, off, 64);
        cg += __shfl_xor(cg, off, 64);
        cb += __shfl_xor(cb, off, 64);
    }

    if (lane == 0) {
        out_rgb[(size_t)ray * 3 + 0] = cr + T_last * bg[0];
        out_rgb[(size_t)ray * 3 + 1] = cg + T_last * bg[1];
        out_rgb[(size_t)ray * 3 + 2] = cb + T_last * bg[2];
        out_alast[ray] = T_last;
    }
}

extern "C" void kernel_launch(void* const* d_in, const int* in_sizes, int n_in,
                              void* d_out, int out_size, void* d_ws, size_t ws_size,
                              hipStream_t stream) {
    const float* density  = (const float*)d_in[0];
    const float* shift    = (const float*)d_in[1];
    const float* rgb      = (const float*)d_in[2];
    const float* bg       = (const float*)d_in[3];
    const int*   interval = (const int*)d_in[4];

    const int n_rays = in_sizes[0] / 256;   // 32768

    float* out = (float*)d_out;
    float* out_rgb     = out;                           // N*3
    float* out_weights = out + (size_t)n_rays * 3;      // N*256
    float* out_alast   = out + (size_t)n_rays * 3 + (size_t)n_rays * 256;  // N

    const int waves_per_block = 4;  // 256 threads
    const int grid = (n_rays + waves_per_block - 1) / waves_per_block;

    march_kernel<<<grid, 256, 0, stream>>>(
        density, shift, rgb, bg, interval,
        out_rgb, out_weights, out_alast, n_rays);
}